// Round 6
// baseline (328.217 us; speedup 1.0000x reference)
//
#include <hip/hip_runtime.h>

// Problem constants
static constexpr int Nn_ = 32, Cc_ = 64, Hh_ = 64, Ww_ = 64;
static constexpr int K_ = 512;
static constexpr int HW_ = Hh_ * Ww_;             // 4096
static constexpr int CHW_ = Cc_ * HW_;            // 262144
static constexpr int T_ = Nn_ * Hh_ * Ww_;        // 131072 tokens
static constexpr int OUT_ELEMS = Nn_ * Cc_ * Hh_ * Ww_;  // 8388608
// d_out layout: [out][codebook_new (32768)][N_new (512)][m_new (32768)]
static constexpr int OFF_CB = OUT_ELEMS;
static constexpr int OFF_N  = OUT_ELEMS + 32768;
static constexpr int OFF_M  = OUT_ELEMS + 32768 + 512;

static constexpr int S_ = 32;   // stats slices == images

// ws layout (floats):
// [0, T_)        idx per token (int)
// [T_, T_+512)   cnorm2
// [WS_PSUM, +S_*512*64)  per-slice partial sums [s][c][k]   (k_stats lifetime)
// [WS_PCNT, +S_*512)     per-slice partial counts [s][k]
// cand_d/cand_i (2*T_ each) OVERLAY the PSUM region: consumed by k_merge
// before k_stats writes psum — disjoint lifetimes, stream-ordered.
static constexpr int WS_IDX    = 0;
static constexpr int WS_CNORM  = T_;
static constexpr int WS_PSUM   = T_ + 512;
static constexpr int WS_PCNT   = WS_PSUM + S_ * K_ * Cc_;
static constexpr int WS_CAND_D = WS_PSUM;            // 2*T_ floats
static constexpr int WS_CAND_I = WS_PSUM + 2 * T_;   // 2*T_ ints

// K0: |c|^2 per codeword
__global__ __launch_bounds__(256) void k_prep(const float* __restrict__ cb,
                                              float* __restrict__ ws) {
    int i = blockIdx.x * 256 + threadIdx.x;
    if (i < K_) {
        const float* r = cb + i * 64;
        float a = 0.f;
#pragma unroll
        for (int j = 0; j < 64; ++j) a = fmaf(r[j], r[j], a);
        ws[WS_CNORM + i] = a;
    }
}

// K1: wave = one (row, k-half). khalf comes from blockIdx -> SGPR by construction
// (R3-R5's wi-derived k-range tainted uniformity and triggered load sinking).
// No LDS, no barriers — faithful to the R2 shape that held xr[64] in VGPRs.
// grid 1024 = 512 row-groups x 2 k-halves; 4 waves/block = 4 rows/block.
__global__ __attribute__((amdgpu_waves_per_eu(3, 4)))
void k_assign(const float* x,                      // NOT restrict: may alias cand_d
              const float* __restrict__ cb,
              const float* __restrict__ cnorm2,
              float* cand_d,                       // NOT restrict
              int* __restrict__ cand_i) {
    const int khalf = blockIdx.x & 1;     // SGPR-uniform k-split
    const int rowg  = blockIdx.x >> 1;    // 0..511
    const int lane  = threadIdx.x & 63;   // w
    const int wi    = threadIdx.x >> 6;   // selects ROW only (vector addresses ok)
    const int row   = rowg * 4 + wi;      // 0..2047  == n*64 + h
    const int n = row >> 6, h = row & 63;
    const int base = n * CHW_ + h * Ww_ + lane;

    // full channel vector for this token (coalesced per channel)
    float xr[64];
#pragma unroll
    for (int c = 0; c < 64; ++c) xr[c] = x[base + c * HW_];

    float xn = 0.f;
#pragma unroll
    for (int c = 0; c < 64; ++c) xn = fmaf(xr[c], xr[c], xn);

    // Volatile may-alias store: x loads cannot sink past it into the k-loop,
    // and volatile blocks dead-store elimination. Overwritten below by this
    // same thread (no race).
    const int slot = khalf * T_ + row * 64 + lane;
    ((volatile float*)cand_d)[slot] = xn;

    const int k0 = khalf * 256;
    float best = __builtin_inff();
    int bidx = k0;
    for (int k = k0; k < k0 + 256; ++k) {
        const float* __restrict__ cr = cb + k * 64;   // uniform -> s_load
        // 4 independent FMA chains (bitwise-identical summation to R4/R5)
        float a0 = 0.f, a1 = 0.f, a2 = 0.f, a3 = 0.f;
#pragma unroll
        for (int j = 0; j < 64; j += 4) {
            a0 = fmaf(xr[j + 0], cr[j + 0], a0);
            a1 = fmaf(xr[j + 1], cr[j + 1], a1);
            a2 = fmaf(xr[j + 2], cr[j + 2], a2);
            a3 = fmaf(xr[j + 3], cr[j + 3], a3);
        }
        float acc = (a0 + a1) + (a2 + a3);
        float d2 = (xn - 2.0f * acc) + cnorm2[k];
        if (d2 < best) { best = d2; bidx = k; }       // strict < == first-min
    }

    cand_d[slot] = best;    // coalesced
    cand_i[slot] = bidx;
}

// K1b: merge the two k-halves, write idx, gather q -> out.
__global__ __launch_bounds__(256) void k_merge(const float* __restrict__ cb,
                                               const float* __restrict__ cand_d,
                                               const int* __restrict__ cand_i,
                                               float* __restrict__ ws,
                                               float* __restrict__ out) {
    int t = blockIdx.x * 256 + threadIdx.x;   // token id
    float d0 = cand_d[t], d1 = cand_d[T_ + t];
    int   i0 = cand_i[t], i1 = cand_i[T_ + t];
    // half0 covers k<256: on ties np.argmin takes the lower k -> strict <
    int bi = (d1 < d0) ? i1 : i0;
    ((int*)(ws + WS_IDX))[t] = bi;            // coalesced

    int base = (t >> 12) * CHW_ + (t & 4095); // n*CHW + h*W + w
    const float* __restrict__ q = cb + bi * 64;  // L1/L2-hot gather
#pragma unroll
    for (int c = 0; c < 64; ++c) {
        out[base + c * HW_] = q[c];           // coalesced store per channel
    }
}

// K2: block = (channel c, image s). float4/int4 coalesced reads, LDS histogram.
__global__ __launch_bounds__(256) void k_stats(const float* __restrict__ x,
                                               const float* __restrict__ ws_ro,
                                               float* __restrict__ ws) {
    const int* __restrict__ idx = (const int*)(ws_ro + WS_IDX);
    __shared__ float hist[512];
    __shared__ float hcnt[512];

    const int c = blockIdx.x & 63;
    const int s = blockIdx.x >> 6;
    const int tid = threadIdx.x;
    const bool docnt = (c == 0);

    hist[tid] = 0.f; hist[tid + 256] = 0.f;
    hcnt[tid] = 0.f; hcnt[tid + 256] = 0.f;
    __syncthreads();

    const float4* __restrict__ xc4 = (const float4*)(x + s * CHW_ + c * HW_);
    const int4*   __restrict__ id4 = (const int4*)(idx + s * HW_);
#pragma unroll
    for (int it = 0; it < 4; ++it) {
        int i = it * 256 + tid;
        int4   ii = id4[i];            // coalesced 16B, L2-hot
        float4 xv = xc4[i];            // coalesced 16B
        atomicAdd(&hist[ii.x], xv.x);
        atomicAdd(&hist[ii.y], xv.y);
        atomicAdd(&hist[ii.z], xv.z);
        atomicAdd(&hist[ii.w], xv.w);
        if (docnt) {
            atomicAdd(&hcnt[ii.x], 1.0f);
            atomicAdd(&hcnt[ii.y], 1.0f);
            atomicAdd(&hcnt[ii.z], 1.0f);
            atomicAdd(&hcnt[ii.w], 1.0f);
        }
    }
    __syncthreads();

    float* psum = ws + WS_PSUM + s * (K_ * Cc_) + c * K_;
    psum[tid] = hist[tid];
    psum[tid + 256] = hist[tid + 256];
    if (docnt) {
        float* pc = ws + WS_PCNT + s * K_;
        pc[tid] = hcnt[tid];
        pc[tid + 256] = hcnt[tid + 256];
    }
}

// K3: reduce slices, finalize EMA states and codebook_new
__global__ __launch_bounds__(256) void k_final(const float* __restrict__ Ns,
                                               const float* __restrict__ ms,
                                               const float* __restrict__ ws,
                                               float* __restrict__ out) {
    int j = blockIdx.x * 256 + threadIdx.x;  // j = c*512 + k  (coalesced partial reads)
    int c = j >> 9, k = j & 511;

    float s = 0.f, cnt = 0.f;
    for (int sl = 0; sl < S_; ++sl) {
        s   += ws[WS_PSUM + sl * (K_ * Cc_) + j];
        cnt += ws[WS_PCNT + sl * K_ + k];
    }

    const float gamma = 0.99f;
    const float omg   = (float)(1.0 - 0.99);

    bool occ = cnt > 0.0f;
    float Nv = Ns[k];
    float Nnew = occ ? (Nv * gamma + cnt * omg) : Nv;

    int i = k * 64 + c;
    float mv = ms[i];
    float mnew = occ ? (mv * gamma + s * omg) : mv;

    out[OFF_CB + i] = mnew / Nnew;
    out[OFF_M  + i] = mnew;
    if (c == 0) out[OFF_N + k] = Nnew;
}

extern "C" void kernel_launch(void* const* d_in, const int* in_sizes, int n_in,
                              void* d_out, int out_size, void* d_ws, size_t ws_size,
                              hipStream_t stream) {
    const float* x  = (const float*)d_in[0];
    const float* cb = (const float*)d_in[1];
    const float* Ns = (const float*)d_in[2];
    const float* ms = (const float*)d_in[3];
    float* out = (float*)d_out;
    float* ws  = (float*)d_ws;

    float* cnorm2 = ws + WS_CNORM;
    float* cand_d = ws + WS_CAND_D;
    int*   cand_i = (int*)(ws + WS_CAND_I);

    hipLaunchKernelGGL(k_prep,   dim3(2),           dim3(256), 0, stream, cb, ws);
    hipLaunchKernelGGL(k_assign, dim3(1024),        dim3(256), 0, stream, x, cb, cnorm2, cand_d, cand_i);
    hipLaunchKernelGGL(k_merge,  dim3(T_ / 256),    dim3(256), 0, stream, cb, cand_d, cand_i, ws, out);
    hipLaunchKernelGGL(k_stats,  dim3(S_ * Cc_),    dim3(256), 0, stream, x, ws, ws);
    hipLaunchKernelGGL(k_final,  dim3(32768 / 256), dim3(256), 0, stream, Ns, ms, ws, out);
}

// Round 7
// 324.932 us; speedup vs baseline: 1.0101x; 1.0101x over previous
//
#include <hip/hip_runtime.h>

// Problem constants
static constexpr int Nn_ = 32, Cc_ = 64, Hh_ = 64, Ww_ = 64;
static constexpr int K_ = 512;
static constexpr int HW_ = Hh_ * Ww_;             // 4096
static constexpr int CHW_ = Cc_ * HW_;            // 262144
static constexpr int T_ = Nn_ * Hh_ * Ww_;        // 131072 tokens
static constexpr int OUT_ELEMS = Nn_ * Cc_ * Hh_ * Ww_;  // 8388608
// d_out layout: [out][codebook_new (32768)][N_new (512)][m_new (32768)]
static constexpr int OFF_CB = OUT_ELEMS;
static constexpr int OFF_N  = OUT_ELEMS + 32768;
static constexpr int OFF_M  = OUT_ELEMS + 32768 + 512;

static constexpr int S_ = 32;   // stats slices == images

// ws layout (floats):
// [0, T_)        idx per token (int)
// [T_, T_+512)   cnorm2
// [WS_PSUM, +S_*512*64)  per-slice partial sums [s][c][k]   (k_stats lifetime)
// [WS_PCNT, +S_*512)     per-slice partial counts [s][k]
// cand_d/cand_i (2*T_ each) OVERLAY the PSUM region: consumed by k_merge
// before k_stats writes psum — disjoint lifetimes, stream-ordered.
static constexpr int WS_IDX    = 0;
static constexpr int WS_CNORM  = T_;
static constexpr int WS_PSUM   = T_ + 512;
static constexpr int WS_PCNT   = WS_PSUM + S_ * K_ * Cc_;
static constexpr int WS_CAND_D = WS_PSUM;            // 2*T_ floats
static constexpr int WS_CAND_I = WS_PSUM + 2 * T_;   // 2*T_ ints

// K0: |c|^2 per codeword
__global__ __launch_bounds__(256) void k_prep(const float* __restrict__ cb,
                                              float* __restrict__ ws) {
    int i = blockIdx.x * 256 + threadIdx.x;
    if (i < K_) {
        const float* r = cb + i * 64;
        float a = 0.f;
#pragma unroll
        for (int j = 0; j < 64; ++j) a = fmaf(r[j], r[j], a);
        ws[WS_CNORM + i] = a;
    }
}

// K1: wave = one (row, k-half). khalf from blockIdx -> SGPR by construction.
// xr[64] pinned in VGPRs via opaque asm (compiler was REMATERIALIZING the x
// loads inside the k-loop every round since R3 -> VGPR 40-52, latency-bound).
// No occupancy attribute: the only build that kept xr resident (R2, VGPR=104)
// had none; every attribute variant (R4/R5/R6) sank or spilled.
__global__ void k_assign(const float* __restrict__ x,
                         const float* __restrict__ cb,
                         const float* __restrict__ cnorm2,
                         float* __restrict__ cand_d,
                         int* __restrict__ cand_i) {
    const int khalf = blockIdx.x & 1;     // SGPR-uniform k-split
    const int rowg  = blockIdx.x >> 1;    // 0..511
    const int lane  = threadIdx.x & 63;   // w
    const int wi    = threadIdx.x >> 6;   // selects ROW only
    const int row   = rowg * 4 + wi;      // 0..2047  == n*64 + h
    const int n = row >> 6, h = row & 63;
    const int base = n * CHW_ + h * Ww_ + lane;

    // full channel vector for this token (coalesced per channel)
    float xr[64];
#pragma unroll
    for (int c = 0; c < 64; ++c) xr[c] = x[base + c * HW_];
    // Opaque pin: each xr[c] becomes asm-defined -> cannot be rematerialized
    // by reloading x inside the k-loop. Zero instructions emitted.
#pragma unroll
    for (int c = 0; c < 64; ++c) asm volatile("" : "+v"(xr[c]));

    float xn = 0.f;
#pragma unroll
    for (int c = 0; c < 64; ++c) xn = fmaf(xr[c], xr[c], xn);

    const int k0 = khalf * 256;
    float best = __builtin_inff();
    int bidx = k0;
    for (int k = k0; k < k0 + 256; ++k) {
        const float* __restrict__ cr = cb + k * 64;   // uniform -> s_load
        // 4 independent FMA chains (summation order identical to R4-R6)
        float a0 = 0.f, a1 = 0.f, a2 = 0.f, a3 = 0.f;
#pragma unroll
        for (int j = 0; j < 64; j += 4) {
            a0 = fmaf(xr[j + 0], cr[j + 0], a0);
            a1 = fmaf(xr[j + 1], cr[j + 1], a1);
            a2 = fmaf(xr[j + 2], cr[j + 2], a2);
            a3 = fmaf(xr[j + 3], cr[j + 3], a3);
        }
        float acc = (a0 + a1) + (a2 + a3);
        float d2 = (xn - 2.0f * acc) + cnorm2[k];
        if (d2 < best) { best = d2; bidx = k; }       // strict < == first-min
    }

    const int slot = khalf * T_ + row * 64 + lane;
    cand_d[slot] = best;    // coalesced
    cand_i[slot] = bidx;
}

// K1b: merge halves + COALESCED q-write via LDS transpose.
// Old version: each lane streamed its own codebook row -> every load touched
// up to 64 cache lines (gather replay), ~8.4M such loads dominated the tail.
// New: lanes=channels read one 256B row per token (single segment), transpose
// through padded LDS, lanes=tokens store coalesced.
__global__ __launch_bounds__(256) void k_merge(const float* __restrict__ cb,
                                               const float* __restrict__ cand_d,
                                               const int* __restrict__ cand_i,
                                               float* __restrict__ ws,
                                               float* __restrict__ out) {
    __shared__ int   bi_s[64];
    __shared__ float tile[64][65];   // [channel][token], +1 pad: conflict-free

    const int row  = blockIdx.x;       // 0..2047 == n*64 + h
    const int lane = threadIdx.x & 63;
    const int wi   = threadIdx.x >> 6;
    const int t0   = row * 64;

    if (threadIdx.x < 64) {
        int t = t0 + threadIdx.x;
        float d0 = cand_d[t], d1 = cand_d[T_ + t];
        int   i0 = cand_i[t], i1 = cand_i[T_ + t];
        int bi = (d1 < d0) ? i1 : i0;   // tie -> lower half == np.argmin
        ((int*)(ws + WS_IDX))[t] = bi;  // coalesced
        bi_s[threadIdx.x] = bi;
    }
    __syncthreads();

    // wave wi gathers rows for tokens [wi*16, wi*16+16)
#pragma unroll
    for (int j = 0; j < 16; ++j) {
        int tt = wi * 16 + j;
        int bi = bi_s[tt];                       // broadcast read
        tile[lane][tt] = cb[bi * 64 + lane];     // one 256B segment per load
    }
    __syncthreads();

    // wave wi stores channels [wi*16, wi*16+16), lanes = tokens (coalesced)
    const int n = row >> 6, h = row & 63;
    const int obase = n * CHW_ + h * Ww_ + lane;
#pragma unroll
    for (int j = 0; j < 16; ++j) {
        int c = wi * 16 + j;
        out[obase + c * HW_] = tile[c][lane];
    }
}

// K2: block = (channel c, image s). float4/int4 coalesced reads, LDS histogram.
__global__ __launch_bounds__(256) void k_stats(const float* __restrict__ x,
                                               const float* __restrict__ ws_ro,
                                               float* __restrict__ ws) {
    const int* __restrict__ idx = (const int*)(ws_ro + WS_IDX);
    __shared__ float hist[512];
    __shared__ float hcnt[512];

    const int c = blockIdx.x & 63;
    const int s = blockIdx.x >> 6;
    const int tid = threadIdx.x;
    const bool docnt = (c == 0);

    hist[tid] = 0.f; hist[tid + 256] = 0.f;
    hcnt[tid] = 0.f; hcnt[tid + 256] = 0.f;
    __syncthreads();

    const float4* __restrict__ xc4 = (const float4*)(x + s * CHW_ + c * HW_);
    const int4*   __restrict__ id4 = (const int4*)(idx + s * HW_);
#pragma unroll
    for (int it = 0; it < 4; ++it) {
        int i = it * 256 + tid;
        int4   ii = id4[i];            // coalesced 16B, L2-hot
        float4 xv = xc4[i];            // coalesced 16B
        atomicAdd(&hist[ii.x], xv.x);
        atomicAdd(&hist[ii.y], xv.y);
        atomicAdd(&hist[ii.z], xv.z);
        atomicAdd(&hist[ii.w], xv.w);
        if (docnt) {
            atomicAdd(&hcnt[ii.x], 1.0f);
            atomicAdd(&hcnt[ii.y], 1.0f);
            atomicAdd(&hcnt[ii.z], 1.0f);
            atomicAdd(&hcnt[ii.w], 1.0f);
        }
    }
    __syncthreads();

    float* psum = ws + WS_PSUM + s * (K_ * Cc_) + c * K_;
    psum[tid] = hist[tid];
    psum[tid + 256] = hist[tid + 256];
    if (docnt) {
        float* pc = ws + WS_PCNT + s * K_;
        pc[tid] = hcnt[tid];
        pc[tid + 256] = hcnt[tid + 256];
    }
}

// K3: reduce slices, finalize EMA states and codebook_new
__global__ __launch_bounds__(256) void k_final(const float* __restrict__ Ns,
                                               const float* __restrict__ ms,
                                               const float* __restrict__ ws,
                                               float* __restrict__ out) {
    int j = blockIdx.x * 256 + threadIdx.x;  // j = c*512 + k  (coalesced partial reads)
    int c = j >> 9, k = j & 511;

    float s = 0.f, cnt = 0.f;
    for (int sl = 0; sl < S_; ++sl) {
        s   += ws[WS_PSUM + sl * (K_ * Cc_) + j];
        cnt += ws[WS_PCNT + sl * K_ + k];
    }

    const float gamma = 0.99f;
    const float omg   = (float)(1.0 - 0.99);

    bool occ = cnt > 0.0f;
    float Nv = Ns[k];
    float Nnew = occ ? (Nv * gamma + cnt * omg) : Nv;

    int i = k * 64 + c;
    float mv = ms[i];
    float mnew = occ ? (mv * gamma + s * omg) : mv;

    out[OFF_CB + i] = mnew / Nnew;
    out[OFF_M  + i] = mnew;
    if (c == 0) out[OFF_N + k] = Nnew;
}

extern "C" void kernel_launch(void* const* d_in, const int* in_sizes, int n_in,
                              void* d_out, int out_size, void* d_ws, size_t ws_size,
                              hipStream_t stream) {
    const float* x  = (const float*)d_in[0];
    const float* cb = (const float*)d_in[1];
    const float* Ns = (const float*)d_in[2];
    const float* ms = (const float*)d_in[3];
    float* out = (float*)d_out;
    float* ws  = (float*)d_ws;

    float* cnorm2 = ws + WS_CNORM;
    float* cand_d = ws + WS_CAND_D;
    int*   cand_i = (int*)(ws + WS_CAND_I);

    hipLaunchKernelGGL(k_prep,   dim3(2),           dim3(256), 0, stream, cb, ws);
    hipLaunchKernelGGL(k_assign, dim3(1024),        dim3(256), 0, stream, x, cb, cnorm2, cand_d, cand_i);
    hipLaunchKernelGGL(k_merge,  dim3(Nn_ * Hh_),   dim3(256), 0, stream, cb, cand_d, cand_i, ws, out);
    hipLaunchKernelGGL(k_stats,  dim3(S_ * Cc_),    dim3(256), 0, stream, x, ws, ws);
    hipLaunchKernelGGL(k_final,  dim3(32768 / 256), dim3(256), 0, stream, Ns, ms, ws, out);
}